// Round 12
// baseline (389.895 us; speedup 1.0000x reference)
//
#include <hip/hip_runtime.h>
#include <math.h>

#define NN 50000
#define MM 800000
#define HH 64
#define NB_EDGE 1024                // 4 blocks/CU exactly (39.4KB LDS x 4 = CU cap)
#define NTILE 12500                 // MM / 64 edges per block-tile

typedef short bf16x8 __attribute__((ext_vector_type(8)));
typedef float f32x4  __attribute__((ext_vector_type(4)));

// hard per-wave LDS drain (node kernel): lgkmcnt(0) + compiler barrier
#define WFENCE() asm volatile("s_waitcnt lgkmcnt(0)" ::: "memory")
// compiler-only barrier (edge kernel): pins code motion (prefetch issue point,
// write-before-read program order) but lets the compiler emit its own
// MINIMAL dependence-tracked lgkmcnt(N) waits. Correctness: all S/RV/RI
// traffic is wave-private and DS ops of one wave are processed in order, so
// program-order issue + data-arrival waits (compiler-inserted) suffice --
// the forced lgkmcnt(0) drains were pure overhead (~5 x 50-100cyc/iter).
#define CFENCE() asm volatile("" ::: "memory")

__device__ __forceinline__ float silu_f(float v) {
    return v * __builtin_amdgcn_rcpf(1.0f + __expf(-v));
}
// round-half-up fp32 -> bf16 bits (0.5 ulp max)
__device__ __forceinline__ unsigned short bfb(float a) {
    return (unsigned short)((__float_as_uint(a) + 0x8000u) >> 16);
}
// pack two f32 -> one u32 of 2 bf16 (low = lo, high = hi), single VALU op
__device__ __forceinline__ unsigned cvtpk(float lo, float hi) {
    unsigned r;
    asm("v_cvt_pk_bf16_f32 %0, %1, %2" : "=v"(r) : "v"(lo), "v"(hi));
    return r;
}
// pack two f32 -> bf16x2 via v_perm (low = a, high = b)
__device__ __forceinline__ unsigned pk2(float a, float b) {
    return __builtin_amdgcn_perm(__float_as_uint(b) + 0x8000u,
                                 __float_as_uint(a) + 0x8000u, 0x07060302u);
}
__device__ __forceinline__ float b2f(unsigned short s) {
    return __uint_as_float((unsigned)s << 16);
}
// packed bf16x2 atomic add
__device__ __forceinline__ void atomic_pk_bf16(unsigned short* addr, unsigned pk) {
    asm volatile("global_atomic_pk_add_bf16 %0, %1, off"
                 :: "v"((unsigned long long)(size_t)addr), "v"(pk) : "memory");
}

// ---------------- fused setup ----------------
// blocks [0,3125): deg histogram
// blocks [3125,3365): weight pre-swizzle (per layer 30720 shorts)
// blocks [3365,15865): embedding (hb only -- f32 h_out is dead, node rewrites)
// blocks [15865,17574): zero sum_f+tmsgb (7,000,000 B)
// blocks [17574,17721): copy x_in -> xo (uint4)
// blocks [17721,17917): build padded x4 mirror
__global__ __launch_bounds__(256) void setup_kernel(
    const int* __restrict__ row, int* __restrict__ deg,
    const float* __restrict__ eW1, const float* __restrict__ eW2,
    const float* __restrict__ cW1, const float* __restrict__ nW1,
    const float* __restrict__ nW2, unsigned short* __restrict__ wsW,
    const float* __restrict__ h_in, const float* __restrict__ emb_W,
    const float* __restrict__ emb_b,
    unsigned short* __restrict__ hb,
    char* __restrict__ zbase, const float* __restrict__ x_in,
    float* __restrict__ xo, float* __restrict__ x4)
{
    const int b = blockIdx.x;
    if (b < 3125) {
        const int e = b * 256 + threadIdx.x;
        atomicAdd(&deg[row[e]], 1);
    } else if (b < 3365) {
        const int i = (b - 3125) * 256 + threadIdx.x;     // 0 .. 61439
        const int layer = i / 30720;
        const int rem = i - layer * 30720;
        float val;
        if (rem < 10240) {
            const int j = rem & 7, lane = (rem >> 3) & 63, nt = (rem >> 9) & 3, s = rem >> 11;
            const int kp = s * 32 + ((lane >> 4) << 3) + j;
            const int n  = nt * 16 + (lane & 15);
            if (kp > 136) val = 0.0f;
            else {
                const int k = (kp == 136) ? 0 : kp + 1;   // k'=136 is the r2 row
                val = eW1[layer * 137 * 64 + k * 64 + n];
            }
        } else if (rem < 14336) {
            const int r2 = rem - 10240;
            const int j = r2 & 7, lane = (r2 >> 3) & 63, nt = (r2 >> 9) & 3, s = r2 >> 11;
            val = eW2[layer * 4096 + (s * 32 + ((lane >> 4) << 3) + j) * 64 + nt * 16 + (lane & 15)];
        } else if (rem < 18432) {
            const int r3 = rem - 14336;
            const int j = r3 & 7, lane = (r3 >> 3) & 63, nt = (r3 >> 9) & 3, s = r3 >> 11;
            val = cW1[layer * 4096 + (s * 32 + ((lane >> 4) << 3) + j) * 64 + nt * 16 + (lane & 15)];
        } else if (rem < 26624) {
            const int r4 = rem - 18432;
            const int j = r4 & 7, lane = (r4 >> 3) & 63, nt = (r4 >> 9) & 3, s = r4 >> 11;
            const int kp = s * 32 + ((lane >> 4) << 3) + j;      // < 128
            val = nW1[layer * 8192 + kp * 64 + nt * 16 + (lane & 15)];
        } else {
            const int r5 = rem - 26624;
            const int j = r5 & 7, lane = (r5 >> 3) & 63, nt = (r5 >> 9) & 3, s = r5 >> 11;
            val = nW2[layer * 4096 + (s * 32 + ((lane >> 4) << 3) + j) * 64 + nt * 16 + (lane & 15)];
        }
        wsW[i] = bfb(val);
    } else if (b < 15865) {
        const int idx = (b - 3365) * 256 + threadIdx.x;   // over N*64
        const int n = idx >> 6, j = idx & 63;
        float acc = emb_b[j];
        #pragma unroll
        for (int k = 0; k < 16; ++k)
            acc += h_in[n * 16 + k] * emb_W[k * HH + j];
        hb[idx] = bfb(acc);
    } else if (b < 17574) {
        const int t = (b - 15865) * 256 + threadIdx.x;
        if (t < 437500) {                                  // 7,000,000 / 16
            const uint4 z = {0u, 0u, 0u, 0u};
            *(uint4*)(zbase + (size_t)t * 16) = z;
        }
    } else if (b < 17721) {
        const int t = (b - 17574) * 256 + threadIdx.x;
        if (t < 37500)                                     // N*3 floats / 4
            ((uint4*)xo)[t] = ((const uint4*)x_in)[t];
    } else {
        const int n = (b - 17721) * 256 + threadIdx.x;
        if (n < NN) {
            float4 v;
            v.x = x_in[3 * n + 0];
            v.y = x_in[3 * n + 1];
            v.z = x_in[3 * n + 2];
            v.w = 0.0f;
            ((float4*)x4)[n] = v;
        }
    }
}

// parallel scan over NN, phase A: 200 blocks x 250-node chunks -> blocksum
__global__ __launch_bounds__(256) void scanA_kernel(const int* __restrict__ deg,
                                                    int* __restrict__ bsum) {
    __shared__ int ps[256];
    const int t = threadIdx.x;
    const int base = blockIdx.x * 250;
    int v = (t < 250) ? deg[base + t] : 0;
    ps[t] = v;
    __syncthreads();
    for (int off = 1; off < 256; off <<= 1) {
        const int u = (t >= off) ? ps[t - off] : 0;
        __syncthreads();
        ps[t] += u;
        __syncthreads();
    }
    if (t == 255) bsum[blockIdx.x] = ps[255];
}

// phase C (scanB folded in): per-chunk scan + in-block prefix of bsum -> cur
__global__ __launch_bounds__(256) void scanC_kernel(const int* __restrict__ deg,
                                                    const int* __restrict__ bsum,
                                                    int* __restrict__ cur) {
    __shared__ int ps[256];
    __shared__ int bs[256];
    const int t = threadIdx.x;
    const int base = blockIdx.x * 250;
    int v = (t < 250) ? deg[base + t] : 0;
    ps[t] = v;
    bs[t] = (t < 200) ? bsum[t] : 0;
    __syncthreads();
    for (int off = 1; off < 256; off <<= 1) {
        const int u1 = (t >= off) ? ps[t - off] : 0;
        const int u2 = (t >= off) ? bs[t - off] : 0;
        __syncthreads();
        ps[t] += u1;
        bs[t] += u2;
        __syncthreads();
    }
    if (t < 250) {
        const int boff = (blockIdx.x > 0) ? bs[blockIdx.x - 1] : 0;  // exclusive
        cur[base + t] = boff + ps[t] - v;   // exclusive prefix
    }
}

// one-pass counting-sort fill: rc (int2 interleaved) + efs in row-sorted order
__global__ __launch_bounds__(256) void fill_kernel(
    const int* __restrict__ row, const int* __restrict__ col,
    const float* __restrict__ efea, int* __restrict__ cur,
    int2* __restrict__ rc, unsigned short* __restrict__ efs)
{
    const int e = blockIdx.x * 256 + threadIdx.x;
    const int r = row[e];
    const int pos = atomicAdd(&cur[r], 1);
    int2 v; v.x = r; v.y = col[e];
    rc[pos] = v;                                       // one 8B scatter
    const float4* ef = (const float4*)(efea + (size_t)e * 8);
    const float4 e0 = ef[0], e1 = ef[1];
    uint4 ue = { pk2(e0.x, e0.y), pk2(e0.z, e0.w), pk2(e1.x, e1.y), pk2(e1.z, e1.w) };
    *(uint4*)(efs + (size_t)pos * 8) = ue;
}

// ---------------- MFMA edge kernel: swapped operands + pipelined gather -----
// R11 structure: swapped MFMAs -- lane (l15,quad) holds D[e=l15][n=...];
// biases folded via ones-fragment K-slices; gather pipelined one tile deep
// reusing the af registers; serial segmented flush (atomic-compressing);
// setprio(1) around MFMA clusters; grid 1024 = 4 blocks/CU. R12: the five
// forced lgkmcnt(0) drains become compiler-only barriers (CFENCE) -- the
// compiler's minimal dependence-tracked waits replace full queue drains
// (same-wave DS ops are processed in order; all S/RV/RI traffic wave-private).
__global__ __launch_bounds__(256, 4) void edge_mfma_kernel(
    const float* __restrict__ x4, const unsigned short* __restrict__ hb,
    const int2* __restrict__ rc, const unsigned short* __restrict__ efs,
    const unsigned short* __restrict__ w1b, const unsigned short* __restrict__ w2b,
    const unsigned short* __restrict__ cw1b,
    const float* __restrict__ b1, const float* __restrict__ b2,
    const float* __restrict__ cb1, const float* __restrict__ cw2,
    const float* __restrict__ cb2,
    float* __restrict__ sum_f, unsigned short* __restrict__ tmsgb)
{
    __shared__ __align__(16) unsigned short S[4][16][72];  // [0,64)=H1/msg, [64,66)=cm f32
    __shared__ float RV[4][16][4];
    __shared__ int   RI[4][16];
    __shared__ __align__(16) unsigned short WS[14336];
    __shared__ __align__(16) float CW2S[64];
    // WS shorts: [0,4096)=w2 s0,s1   [4096,6144)=w2 bias slice
    //            [6144,10240)=cw1 s0,s1  [10240,12288)=cw1 bias slice
    //            [12288,14336)=w1 slice4 (kp137 patched with b1)

    const int tid = threadIdx.x;
    const int w = tid >> 6, lane = tid & 63;
    const int l15 = lane & 15, quad = lane >> 4;

    // stage weights + bias slices into LDS, block-shared
    {
        const uint4* s2 = (const uint4*)w2b;
        const uint4* s3 = (const uint4*)cw1b;
        const uint4* s4 = (const uint4*)w1b;   // slice4 = uint4 idx [1024,1280)
        uint4* dst = (uint4*)WS;
        dst[tid]        = s2[tid];
        dst[256 + tid]  = s2[256 + tid];
        dst[768 + tid]  = s3[tid];
        dst[1024 + tid] = s3[256 + tid];
        const int ln = tid & 63, ntb = tid >> 6;
        uint4 z4 = s4[1024 + tid];
        if ((ln >> 4) == 1)    // quad==1, j==1 slot = kp137 (high half of .x)
            z4.x = (z4.x & 0x0000FFFFu) | ((unsigned)bfb(b1[ntb * 16 + (ln & 15)]) << 16);
        dst[1536 + tid] = z4;
        uint4 zb = {0u, 0u, 0u, 0u};
        if ((ln >> 4) == 0) zb.x = (unsigned)bfb(b2[ntb * 16 + (ln & 15)]);
        dst[512 + tid] = zb;
        uint4 zc = {0u, 0u, 0u, 0u};
        if ((ln >> 4) == 0) zc.x = (unsigned)bfb(cb1[ntb * 16 + (ln & 15)]);
        dst[1280 + tid] = zc;
        if (tid < 64) CW2S[tid] = cw2[tid];
    }

    // hoist W1 slices 0..3 into registers (loop-invariant; AGPR-parked, 64)
    bf16x8 w1f[4][4];
    #pragma unroll
    for (int s = 0; s < 4; ++s)
        #pragma unroll
        for (int nt = 0; nt < 4; ++nt)
            w1f[s][nt] = *(const bf16x8*)(w1b + ((s * 4 + nt) * 64 + lane) * 8);

    const float cb2s = cb2[0];

    // ones B-fragment: B[k=0][e]=1 for all e (bias K-slice driver)
    bf16x8 onef = {0, 0, 0, 0, 0, 0, 0, 0};
    if (quad == 0) onef[0] = (short)0x3F80;

    __syncthreads();   // WS/CW2S visible to all 4 waves

    // ---- pipeline prologue: rc for tile 0 and 1, payload for tile 0 ----
    int bt  = blockIdx.x;
    int btn = bt + NB_EDGE;
    int2 rcv = rc[(bt * 4 + w) * 16 + l15];
    int2 rcn = rc[((btn < NTILE ? btn : bt) * 4 + w) * 16 + l15];
    bf16x8 af0, af1, af2, af3;
    bf16x8 af4 = {0, 0, 0, 0, 0, 0, 0, 0};
    {
        const unsigned short* hr = hb + (size_t)rcv.x * HH + quad * 8;
        const unsigned short* hc = hb + (size_t)rcv.y * HH + quad * 8;
        af0 = *(const bf16x8*)(hr);
        af1 = *(const bf16x8*)(hr + 32);
        af2 = *(const bf16x8*)(hc);
        af3 = *(const bf16x8*)(hc + 32);
        if (quad == 0)
            af4 = *(const bf16x8*)(efs + (size_t)((bt * 4 + w) * 16 + l15) * 8);
    }

    while (bt < NTILE) {
        // ---- consume: per-tile scalars (x4 read not prefetched; its latency
        // hides under G1's first 16 MFMAs since af4 only feeds the last slice)
        if (quad == 0) {
            RI[w][l15] = rcv.x;
        } else if (quad == 1) {
            const float4 xr = ((const float4*)x4)[rcv.x];
            const float4 xc = ((const float4*)x4)[rcv.y];
            const float rx = xr.x - xc.x;
            const float ry = xr.y - xc.y;
            const float rz = xr.z - xc.z;
            RV[w][l15][0] = rx; RV[w][l15][1] = ry; RV[w][l15][2] = rz;
            af4[0] = (short)bfb(rx * rx + ry * ry + rz * rz);
            af4[1] = (short)0x3F80;   // kp=137 constant-1 -> b1 bias row
        }

        // ---- GEMM1 swapped: lane holds H1[l15][nt*16+quad*4+rr] ----
        __builtin_amdgcn_s_setprio(1);
        #pragma unroll
        for (int nt = 0; nt < 4; ++nt) {
            f32x4 a = {0.f, 0.f, 0.f, 0.f};
            a = __builtin_amdgcn_mfma_f32_16x16x32_bf16(w1f[0][nt], af0, a, 0, 0, 0);
            a = __builtin_amdgcn_mfma_f32_16x16x32_bf16(w1f[1][nt], af1, a, 0, 0, 0);
            a = __builtin_amdgcn_mfma_f32_16x16x32_bf16(w1f[2][nt], af2, a, 0, 0, 0);
            a = __builtin_amdgcn_mfma_f32_16x16x32_bf16(w1f[3][nt], af3, a, 0, 0, 0);
            {
                bf16x8 b4 = *(const bf16x8*)&WS[12288 + (nt * 64 + lane) * 8];
                a = __builtin_amdgcn_mfma_f32_16x16x32_bf16(b4, af4, a, 0, 0, 0);
            }
            uint2 pkv;
            pkv.x = cvtpk(silu_f(a[0]), silu_f(a[1]));
            pkv.y = cvtpk(silu_f(a[2]), silu_f(a[3]));
            *(uint2*)&S[w][l15][nt * 16 + quad * 4] = pkv;   // row=e, cols n..n+3
        }
        __builtin_amdgcn_s_setprio(0);

        // ---- issue next tile's payload into the now-dead af regs ----
        {
            const int pn = ((btn < NTILE ? btn : bt) * 4 + w) * 16 + l15;
            const unsigned short* hr = hb + (size_t)rcn.x * HH + quad * 8;
            const unsigned short* hc = hb + (size_t)rcn.y * HH + quad * 8;
            af0 = *(const bf16x8*)(hr);
            af1 = *(const bf16x8*)(hr + 32);
            af2 = *(const bf16x8*)(hc);
            af3 = *(const bf16x8*)(hc + 32);
            if (quad == 0)
                af4 = *(const bf16x8*)(efs + (size_t)pn * 8);
        }
        const int btn2 = btn + NB_EDGE;
        const int2 rcn2 = rc[((btn2 < NTILE ? btn2 : btn) * 4 + w) * 16 + l15];
        CFENCE();

        // ---- GEMM2 swapped: B-frags = H1[l15][s*32+quad*8..] from S ----
        bf16x8 h1f0 = *(const bf16x8*)&S[w][l15][quad * 8];
        bf16x8 h1f1 = *(const bf16x8*)&S[w][l15][32 + quad * 8];
        CFENCE();   // frags read (program-order) before msg overwrites
        __builtin_amdgcn_s_setprio(1);
        #pragma unroll
        for (int nt = 0; nt < 4; ++nt) {
            f32x4 m = {0.f, 0.f, 0.f, 0.f};
            {
                bf16x8 wf = *(const bf16x8*)&WS[((0 * 4 + nt) * 64 + lane) * 8];
                m = __builtin_amdgcn_mfma_f32_16x16x32_bf16(wf, h1f0, m, 0, 0, 0);
            }
            {
                bf16x8 wf = *(const bf16x8*)&WS[((1 * 4 + nt) * 64 + lane) * 8];
                m = __builtin_amdgcn_mfma_f32_16x16x32_bf16(wf, h1f1, m, 0, 0, 0);
            }
            {
                bf16x8 wb = *(const bf16x8*)&WS[4096 + (nt * 64 + lane) * 8];
                m = __builtin_amdgcn_mfma_f32_16x16x32_bf16(wb, onef, m, 0, 0, 0);
            }
            uint2 pkv;
            pkv.x = cvtpk(silu_f(m[0]), silu_f(m[1]));
            pkv.y = cvtpk(silu_f(m[2]), silu_f(m[3]));
            *(uint2*)&S[w][l15][nt * 16 + quad * 4] = pkv;   // msg[e][n]
        }
        __builtin_amdgcn_s_setprio(0);
        CFENCE();

        // ---- GEMM3 swapped: c1[l15][n]; lane-local dot with cw2 (LDS) ----
        bf16x8 mf0 = *(const bf16x8*)&S[w][l15][quad * 8];
        bf16x8 mf1 = *(const bf16x8*)&S[w][l15][32 + quad * 8];
        float pr = 0.f;
        __builtin_amdgcn_s_setprio(1);
        #pragma unroll
        for (int nt = 0; nt < 4; ++nt) {
            f32x4 q3 = {0.f, 0.f, 0.f, 0.f};
            {
                bf16x8 wf = *(const bf16x8*)&WS[6144 + ((0 * 4 + nt) * 64 + lane) * 8];
                q3 = __builtin_amdgcn_mfma_f32_16x16x32_bf16(wf, mf0, q3, 0, 0, 0);
            }
            {
                bf16x8 wf = *(const bf16x8*)&WS[6144 + ((1 * 4 + nt) * 64 + lane) * 8];
                q3 = __builtin_amdgcn_mfma_f32_16x16x32_bf16(wf, mf1, q3, 0, 0, 0);
            }
            {
                bf16x8 wb = *(const bf16x8*)&WS[10240 + (nt * 64 + lane) * 8];
                q3 = __builtin_amdgcn_mfma_f32_16x16x32_bf16(wb, onef, q3, 0, 0, 0);
            }
            const float4 cwv = *(const float4*)&CW2S[nt * 16 + quad * 4];
            pr += silu_f(q3[0]) * cwv.x;
            pr += silu_f(q3[1]) * cwv.y;
            pr += silu_f(q3[2]) * cwv.z;
            pr += silu_f(q3[3]) * cwv.w;
        }
        __builtin_amdgcn_s_setprio(0);
        pr += __shfl_xor(pr, 16, 64);    // reduce over the 4 quads of edge l15
        pr += __shfl_xor(pr, 32, 64);
        if (quad == 0) *(float*)&S[w][l15][64] = pr + cb2s;
        CFENCE();

        // ---- segmented flush: rows sorted by RI within the tile ----
        if (lane < 32) {   // msg -> tmsgb: lane owns cols {2l, 2l+1}, pk atomic
            unsigned both = *(const unsigned*)&S[w][0][2 * lane];
            float ax = b2f((unsigned short)(both & 0xffffu));
            float ay = b2f((unsigned short)(both >> 16));
            int cur_r = RI[w][0];
            #pragma unroll
            for (int g = 1; g < 16; ++g) {
                const int ri = RI[w][g];
                unsigned bv = *(const unsigned*)&S[w][g][2 * lane];
                const float vx = b2f((unsigned short)(bv & 0xffffu));
                const float vy = b2f((unsigned short)(bv >> 16));
                if (ri != cur_r) {
                    atomic_pk_bf16(&tmsgb[(size_t)cur_r * HH + 2 * lane], pk2(ax, ay));
                    ax = 0.f; ay = 0.f; cur_r = ri;
                }
                ax += vx; ay += vy;
            }
            atomic_pk_bf16(&tmsgb[(size_t)cur_r * HH + 2 * lane], pk2(ax, ay));
        } else if ((lane & 31) < 3) {   // f = rij*cm -> sum_f (fp32, tiny)
            const int sl = lane & 31;
            float acc = RV[w][0][sl] * (*(const float*)&S[w][0][64]);
            int cur_r = RI[w][0];
            #pragma unroll
            for (int g = 1; g < 16; ++g) {
                const int ri = RI[w][g];
                const float v = RV[w][g][sl] * (*(const float*)&S[w][g][64]);
                if (ri != cur_r) {
                    atomicAdd(&sum_f[3 * cur_r + sl], acc);
                    acc = 0.f; cur_r = ri;
                }
                acc += v;
            }
            atomicAdd(&sum_f[3 * cur_r + sl], acc);
        }
        CFENCE();   // flush reads ordered (program order) before next S writes

        // ---- rotate pipeline state ----
        bt = btn; btn = btn2; rcv = rcn; rcn = rcn2;
    }
}

// ---------------- MFMA node kernel: 16 nodes per wave ----------------
// Reads bf16 tmsgb directly. `last` guards dead cross-layer work:
//  layer 0 (!last): skip the f32 h store (layer 1 rewrites it); keep hb, x4,
//    and tmsgb/sum_f re-zeroing (layer 1 needs them).
//  layer 1 (last): write h + x only; skip hb, x4, and the re-zeroing
//    (setup re-zeroes on every launch, so iteration re-runs stay correct).
__global__ __launch_bounds__(256) void node_mfma_kernel(
    float* __restrict__ x, float* __restrict__ x4, float* __restrict__ h,
    unsigned short* __restrict__ hb,
    float* __restrict__ sum_f, const int* __restrict__ deg,
    unsigned short* __restrict__ tmsgb,
    const unsigned short* __restrict__ nw1b, const unsigned short* __restrict__ nw2b,
    const float* __restrict__ nb1, const float* __restrict__ nb2, int last)
{
    __shared__ __align__(16) unsigned short S[4][16][136];
    const int tid = threadIdx.x;
    const int w = tid >> 6, lane = tid & 63;
    const int l15 = lane & 15, quad = lane >> 4;
    const int le = lane >> 2, sub = lane & 3;
    const int t = blockIdx.x * 4 + w;
    if (t >= NN / 16) return;                      // 3125 waves exactly

    // gather (fully coalesced): [hb | tmsgb] -> S[16][128]; zero tmsgb after
    {
        unsigned short* Srow = &S[w][le][0];
        const int n = t * 16 + le;
        const unsigned short* hr = hb + (size_t)n * HH + sub * 16;
        *(uint4*)&Srow[sub * 16]     = *(const uint4*)(hr);
        *(uint4*)&Srow[sub * 16 + 8] = *(const uint4*)(hr + 8);
        unsigned short* tm = tmsgb + (size_t)n * HH + sub * 16;
        *(uint4*)&Srow[64 + sub * 16]     = *(const uint4*)(tm);
        *(uint4*)&Srow[64 + sub * 16 + 8] = *(const uint4*)(tm + 8);
        if (!last) {
            const uint4 z = {0u, 0u, 0u, 0u};
            *(uint4*)(tm)     = z;
            *(uint4*)(tm + 8) = z;
        }
    }
    // x update: one lane per node; zero sum_f after (unless last layer)
    if (lane < 16) {
        const int nn = t * 16 + lane;
        const float cn = fmaxf((float)deg[nn], 1.0f);
        const float rc = __builtin_amdgcn_rcpf(cn);
        #pragma unroll
        for (int d3 = 0; d3 < 3; ++d3) {
            float tf = sum_f[3 * nn + d3] * rc;
            tf = fminf(fmaxf(tf, -100.0f), 100.0f);
            x[3 * nn + d3] += tf;
            if (!last) {
                x4[4 * nn + d3] += tf;
                sum_f[3 * nn + d3] = 0.0f;
            }
        }
    }
    WFENCE();

    // GEMM1: [16x128] @ nW1[128x64] -> SiLU -> alias cols 0..63
    bf16x8 af[4];
    #pragma unroll
    for (int s = 0; s < 4; ++s)
        af[s] = *(const bf16x8*)&S[w][l15][s * 32 + quad * 8];
    WFENCE();
    float nb1v[4], nb2v[4];
    #pragma unroll
    for (int nt = 0; nt < 4; ++nt) {
        nb1v[nt] = nb1[nt * 16 + l15];
        nb2v[nt] = nb2[nt * 16 + l15];
    }
    #pragma unroll
    for (int nt = 0; nt < 4; ++nt) {
        f32x4 a = {0.f, 0.f, 0.f, 0.f};
        #pragma unroll
        for (int s = 0; s < 4; ++s) {
            bf16x8 bf = *(const bf16x8*)(nw1b + ((s * 4 + nt) * 64 + lane) * 8);
            a = __builtin_amdgcn_mfma_f32_16x16x32_bf16(af[s], bf, a, 0, 0, 0);
        }
        #pragma unroll
        for (int rr = 0; rr < 4; ++rr)
            S[w][quad * 4 + rr][nt * 16 + l15] = bfb(silu_f(a[rr] + nb1v[nt]));
    }
    WFENCE();

    // GEMM2: [16x64] @ nW2[64x64] -> h (no act)
    bf16x8 a2[2];
    #pragma unroll
    for (int s = 0; s < 2; ++s)
        a2[s] = *(const bf16x8*)&S[w][l15][s * 32 + quad * 8];
    #pragma unroll
    for (int nt = 0; nt < 4; ++nt) {
        f32x4 m = {0.f, 0.f, 0.f, 0.f};
        #pragma unroll
        for (int s = 0; s < 2; ++s) {
            bf16x8 bf = *(const bf16x8*)(nw2b + ((s * 4 + nt) * 64 + lane) * 8);
            m = __builtin_amdgcn_mfma_f32_16x16x32_bf16(a2[s], bf, m, 0, 0, 0);
        }
        #pragma unroll
        for (int rr = 0; rr < 4; ++rr) {
            const float v = m[rr] + nb2v[nt];
            const size_t nd = (size_t)(t * 16 + quad * 4 + rr) * HH + nt * 16 + l15;
            if (last) h[nd] = v;
            else      hb[nd] = bfb(v);
        }
    }
}

extern "C" void kernel_launch(void* const* d_in, const int* in_sizes, int n_in,
                              void* d_out, int out_size, void* d_ws, size_t ws_size,
                              hipStream_t stream) {
    const float* x_in  = (const float*)d_in[0];
    const float* h_in  = (const float*)d_in[1];
    const int*   row   = (const int*)d_in[2];
    const int*   col   = (const int*)d_in[3];
    const float* efea  = (const float*)d_in[4];
    const float* emb_W = (const float*)d_in[5];
    const float* emb_b = (const float*)d_in[6];
    const float* eW1   = (const float*)d_in[7];
    const float* eb1   = (const float*)d_in[8];
    const float* eW2   = (const float*)d_in[9];
    const float* eb2   = (const float*)d_in[10];
    const float* cW1   = (const float*)d_in[11];
    const float* cb1   = (const float*)d_in[12];
    const float* cW2   = (const float*)d_in[13];
    const float* cb2   = (const float*)d_in[14];
    const float* nW1   = (const float*)d_in[15];
    const float* nb1   = (const float*)d_in[16];
    const float* nW2   = (const float*)d_in[17];
    const float* nb2   = (const float*)d_in[18];

    float* out = (float*)d_out;
    float* xo = out;                 // N*3
    float* ho = out + NN * 3;        // N*64

    // workspace layout (16B-aligned segments)
    char* wsb = (char*)d_ws;
    float* sum_f = (float*)wsb;                                  //    600,000 B
    unsigned short* tmsgb = (unsigned short*)(wsb + 600000);     //  6,400,000 B
    unsigned short* efs = (unsigned short*)(wsb + 7000000);      // 12,800,000 B
    unsigned short* hb  = (unsigned short*)(wsb + 19800000);     //  6,400,000 B
    unsigned short* wsW = (unsigned short*)(wsb + 26200000);     //    122,880 B
    int* deg    = (int*)(wsb + 26322880);                        //    200,000 B
    int* cur    = (int*)(wsb + 26522880);                        //    200,000 B
    int2* rc    = (int2*)(wsb + 26722880);                       //  6,400,000 B
    float* x4   = (float*)(wsb + 33122880);                      //    800,000 B
    int* bsum   = (int*)(wsb + 33922880);                        //        800 B

    // zero deg, then fused setup (hist + swizzle + embed + zero + x copies)
    hipMemsetAsync(deg, 0, 200000, stream);
    setup_kernel<<<17917, 256, 0, stream>>>(
        row, deg,
        eW1, eW2, cW1, nW1, nW2, wsW,
        h_in, emb_W, emb_b, hb,
        wsb, x_in, xo, x4);
    // row scan + counting sort (scanB folded into scanC)
    scanA_kernel<<<200, 256, 0, stream>>>(deg, bsum);
    scanC_kernel<<<200, 256, 0, stream>>>(deg, bsum, cur);
    fill_kernel<<<MM / 256, 256, 0, stream>>>(row, col, efea, cur, rc, efs);

    for (int i = 0; i < 2; ++i) {
        const unsigned short* L = wsW + i * 30720;
        edge_mfma_kernel<<<NB_EDGE, 256, 0, stream>>>(
            x4, hb, rc, efs,
            L, L + 10240, L + 14336,
            eb1 + i * 64, eb2 + i * 64, cb1 + i * 64, cW2 + i * 64, cb2 + i,
            sum_f, tmsgb);
        node_mfma_kernel<<<(NN / 16 + 3) / 4, 256, 0, stream>>>(
            xo, x4, ho, hb, sum_f, deg, tmsgb,
            L + 18432, L + 26624, nb1 + i * 64, nb2 + i * 64, i);
    }
}

// Round 13
// 387.686 us; speedup vs baseline: 1.0057x; 1.0057x over previous
//
#include <hip/hip_runtime.h>
#include <math.h>

#define NN 50000
#define MM 800000
#define HH 64
#define NB_EDGE 1024                // 4 blocks/CU exactly (39.4KB LDS x 4 = CU cap)
#define NTILE 12500                 // MM / 64 edges per block-tile

typedef short bf16x8 __attribute__((ext_vector_type(8)));
typedef float f32x4  __attribute__((ext_vector_type(4)));

// hard per-wave LDS drain (node kernel): lgkmcnt(0) + compiler barrier
#define WFENCE() asm volatile("s_waitcnt lgkmcnt(0)" ::: "memory")
// compiler-only barrier (edge kernel): pins code motion but lets the compiler
// emit minimal dependence-tracked lgkmcnt(N) waits (R12: -3us/dispatch).
#define CFENCE() asm volatile("" ::: "memory")

__device__ __forceinline__ float silu_f(float v) {
    return v * __builtin_amdgcn_rcpf(1.0f + __expf(-v));
}
// round-half-up fp32 -> bf16 bits (0.5 ulp max)
__device__ __forceinline__ unsigned short bfb(float a) {
    return (unsigned short)((__float_as_uint(a) + 0x8000u) >> 16);
}
// pack two f32 -> one u32 of 2 bf16 (low = lo, high = hi), single VALU op
__device__ __forceinline__ unsigned cvtpk(float lo, float hi) {
    unsigned r;
    asm("v_cvt_pk_bf16_f32 %0, %1, %2" : "=v"(r) : "v"(lo), "v"(hi));
    return r;
}
// pack two f32 -> bf16x2 via v_perm (low = a, high = b)
__device__ __forceinline__ unsigned pk2(float a, float b) {
    return __builtin_amdgcn_perm(__float_as_uint(b) + 0x8000u,
                                 __float_as_uint(a) + 0x8000u, 0x07060302u);
}
__device__ __forceinline__ float b2f(unsigned short s) {
    return __uint_as_float((unsigned)s << 16);
}
// packed bf16x2 atomic add
__device__ __forceinline__ void atomic_pk_bf16(unsigned short* addr, unsigned pk) {
    asm volatile("global_atomic_pk_add_bf16 %0, %1, off"
                 :: "v"((unsigned long long)(size_t)addr), "v"(pk) : "memory");
}
// load the 16B ef payload of a 24B edge record (8B-aligned) as a bf16x8
__device__ __forceinline__ bf16x8 ld_ef(const char* rp) {
    union { uint2 u[2]; bf16x8 v; } t;
    t.u[0] = *(const uint2*)(rp + 8);
    t.u[1] = *(const uint2*)(rp + 16);
    return t.v;
}

// ---------------- fused setup ----------------
// blocks [0,3125): deg histogram
// blocks [3125,3365): weight pre-swizzle (per layer 30720 shorts)
// blocks [3365,9615): embedding, 2 outputs/thread (hb only; f32 h is dead)
// blocks [9615,11324): zero sum_f+tmsgb (7,000,000 B)
// blocks [11324,11471): copy x_in -> xo (uint4)
// blocks [11471,11667): build padded x4 mirror
__global__ __launch_bounds__(256) void setup_kernel(
    const int* __restrict__ row, int* __restrict__ deg,
    const float* __restrict__ eW1, const float* __restrict__ eW2,
    const float* __restrict__ cW1, const float* __restrict__ nW1,
    const float* __restrict__ nW2, unsigned short* __restrict__ wsW,
    const float* __restrict__ h_in, const float* __restrict__ emb_W,
    const float* __restrict__ emb_b,
    unsigned short* __restrict__ hb,
    char* __restrict__ zbase, const float* __restrict__ x_in,
    float* __restrict__ xo, float* __restrict__ x4)
{
    const int b = blockIdx.x;
    if (b < 3125) {
        const int e = b * 256 + threadIdx.x;
        atomicAdd(&deg[row[e]], 1);
    } else if (b < 3365) {
        const int i = (b - 3125) * 256 + threadIdx.x;     // 0 .. 61439
        const int layer = i / 30720;
        const int rem = i - layer * 30720;
        float val;
        if (rem < 10240) {
            const int j = rem & 7, lane = (rem >> 3) & 63, nt = (rem >> 9) & 3, s = rem >> 11;
            const int kp = s * 32 + ((lane >> 4) << 3) + j;
            const int n  = nt * 16 + (lane & 15);
            if (kp > 136) val = 0.0f;
            else {
                const int k = (kp == 136) ? 0 : kp + 1;   // k'=136 is the r2 row
                val = eW1[layer * 137 * 64 + k * 64 + n];
            }
        } else if (rem < 14336) {
            const int r2 = rem - 10240;
            const int j = r2 & 7, lane = (r2 >> 3) & 63, nt = (r2 >> 9) & 3, s = r2 >> 11;
            val = eW2[layer * 4096 + (s * 32 + ((lane >> 4) << 3) + j) * 64 + nt * 16 + (lane & 15)];
        } else if (rem < 18432) {
            const int r3 = rem - 14336;
            const int j = r3 & 7, lane = (r3 >> 3) & 63, nt = (r3 >> 9) & 3, s = r3 >> 11;
            val = cW1[layer * 4096 + (s * 32 + ((lane >> 4) << 3) + j) * 64 + nt * 16 + (lane & 15)];
        } else if (rem < 26624) {
            const int r4 = rem - 18432;
            const int j = r4 & 7, lane = (r4 >> 3) & 63, nt = (r4 >> 9) & 3, s = r4 >> 11;
            const int kp = s * 32 + ((lane >> 4) << 3) + j;      // < 128
            val = nW1[layer * 8192 + kp * 64 + nt * 16 + (lane & 15)];
        } else {
            const int r5 = rem - 26624;
            const int j = r5 & 7, lane = (r5 >> 3) & 63, nt = (r5 >> 9) & 3, s = r5 >> 11;
            val = nW2[layer * 4096 + (s * 32 + ((lane >> 4) << 3) + j) * 64 + nt * 16 + (lane & 15)];
        }
        wsW[i] = bfb(val);
    } else if (b < 9615) {
        const int idx = (b - 3365) * 256 + threadIdx.x;   // over N*32
        const int n = idx >> 5, j2 = (idx & 31) * 2;
        float a0 = emb_b[j2], a1 = emb_b[j2 + 1];
        #pragma unroll
        for (int k = 0; k < 16; ++k) {
            const float hv = h_in[n * 16 + k];
            a0 += hv * emb_W[k * HH + j2];
            a1 += hv * emb_W[k * HH + j2 + 1];
        }
        *(unsigned*)&hb[n * HH + j2] = pk2(a0, a1);
    } else if (b < 11324) {
        const int t = (b - 9615) * 256 + threadIdx.x;
        if (t < 437500) {                                  // 7,000,000 / 16
            const uint4 z = {0u, 0u, 0u, 0u};
            *(uint4*)(zbase + (size_t)t * 16) = z;
        }
    } else if (b < 11471) {
        const int t = (b - 11324) * 256 + threadIdx.x;
        if (t < 37500)                                     // N*3 floats / 4
            ((uint4*)xo)[t] = ((const uint4*)x_in)[t];
    } else {
        const int n = (b - 11471) * 256 + threadIdx.x;
        if (n < NN) {
            float4 v;
            v.x = x_in[3 * n + 0];
            v.y = x_in[3 * n + 1];
            v.z = x_in[3 * n + 2];
            v.w = 0.0f;
            ((float4*)x4)[n] = v;
        }
    }
}

// fused scan (replaces scanA+scanB+scanC): 200 blocks, all co-resident.
// Each block scans its 250-node chunk, publishes its total to gs[b] (flag =
// sum+1, device-scope atomic), then spin-waits for all predecessors' totals
// (decoupled lookback; 200 blocks <= 256 CUs so all make progress), reduces
// them, and writes the exclusive global prefix into cur.
__global__ __launch_bounds__(256) void scan_kernel(const int* __restrict__ deg,
                                                   int* __restrict__ gs,
                                                   int* __restrict__ cur) {
    __shared__ int ps[256];
    __shared__ int red[4];
    const int t = threadIdx.x;
    const int b = blockIdx.x;
    const int base = b * 250;
    int v = (t < 250) ? deg[base + t] : 0;
    ps[t] = v;
    __syncthreads();
    for (int off = 1; off < 256; off <<= 1) {
        const int u = (t >= off) ? ps[t - off] : 0;
        __syncthreads();
        ps[t] += u;
        __syncthreads();
    }
    if (t == 255) atomicExch(&gs[b], ps[255] + 1);   // publish chunk total
    int pre = 0;
    if (t < b) {                                     // lookback on predecessors
        int u;
        do { u = atomicAdd(&gs[t], 0); } while (u == 0);
        pre = u - 1;
    }
    #pragma unroll
    for (int o = 1; o < 64; o <<= 1) pre += __shfl_xor(pre, o, 64);
    if ((t & 63) == 0) red[t >> 6] = pre;
    __syncthreads();
    if (t < 250) {
        const int boff = red[0] + red[1] + red[2] + red[3];
        cur[base + t] = boff + ps[t] - v;            // exclusive global prefix
    }
}

// one-pass counting-sort fill: ONE combined 24B record per edge
// [r:4 | c:4 | ef: 8 x bf16] written contiguously -- one cache-line touch for
// ~63% of edges (vs 2 lines with the old split rc/efs arrays).
__global__ __launch_bounds__(256) void fill_kernel(
    const int* __restrict__ row, const int* __restrict__ col,
    const float* __restrict__ efea, int* __restrict__ cur,
    char* __restrict__ rce)
{
    const int e = blockIdx.x * 256 + threadIdx.x;
    const int r = row[e];
    const int pos = atomicAdd(&cur[r], 1);
    char* rp = rce + (size_t)pos * 24;
    int2 v; v.x = r; v.y = col[e];
    *(int2*)rp = v;
    const float4* ef = (const float4*)(efea + (size_t)e * 8);
    const float4 e0 = ef[0], e1 = ef[1];
    uint2 p0; p0.x = pk2(e0.x, e0.y); p0.y = pk2(e0.z, e0.w);
    uint2 p1; p1.x = pk2(e1.x, e1.y); p1.y = pk2(e1.z, e1.w);
    *(uint2*)(rp + 8)  = p0;
    *(uint2*)(rp + 16) = p1;
}

// ---------------- MFMA edge kernel: swapped operands + pipelined gather -----
// R12 structure: swapped MFMAs -- lane (l15,quad) holds D[e=l15][n=...];
// biases folded via ones-fragment K-slices; gather pipelined one tile deep
// reusing the af registers; serial segmented flush; setprio around MFMA
// clusters; CFENCE (compiler-minimal waits); grid 1024 = 4 blocks/CU.
// R13: reads the combined 24B edge record (r,c at +0, ef at +8).
__global__ __launch_bounds__(256, 4) void edge_mfma_kernel(
    const float* __restrict__ x4, const unsigned short* __restrict__ hb,
    const char* __restrict__ rce,
    const unsigned short* __restrict__ w1b, const unsigned short* __restrict__ w2b,
    const unsigned short* __restrict__ cw1b,
    const float* __restrict__ b1, const float* __restrict__ b2,
    const float* __restrict__ cb1, const float* __restrict__ cw2,
    const float* __restrict__ cb2,
    float* __restrict__ sum_f, unsigned short* __restrict__ tmsgb)
{
    __shared__ __align__(16) unsigned short S[4][16][72];  // [0,64)=H1/msg, [64,66)=cm f32
    __shared__ float RV[4][16][4];
    __shared__ int   RI[4][16];
    __shared__ __align__(16) unsigned short WS[14336];
    __shared__ __align__(16) float CW2S[64];
    // WS shorts: [0,4096)=w2 s0,s1   [4096,6144)=w2 bias slice
    //            [6144,10240)=cw1 s0,s1  [10240,12288)=cw1 bias slice
    //            [12288,14336)=w1 slice4 (kp137 patched with b1)

    const int tid = threadIdx.x;
    const int w = tid >> 6, lane = tid & 63;
    const int l15 = lane & 15, quad = lane >> 4;

    // stage weights + bias slices into LDS, block-shared
    {
        const uint4* s2 = (const uint4*)w2b;
        const uint4* s3 = (const uint4*)cw1b;
        const uint4* s4 = (const uint4*)w1b;   // slice4 = uint4 idx [1024,1280)
        uint4* dst = (uint4*)WS;
        dst[tid]        = s2[tid];
        dst[256 + tid]  = s2[256 + tid];
        dst[768 + tid]  = s3[tid];
        dst[1024 + tid] = s3[256 + tid];
        const int ln = tid & 63, ntb = tid >> 6;
        uint4 z4 = s4[1024 + tid];
        if ((ln >> 4) == 1)    // quad==1, j==1 slot = kp137 (high half of .x)
            z4.x = (z4.x & 0x0000FFFFu) | ((unsigned)bfb(b1[ntb * 16 + (ln & 15)]) << 16);
        dst[1536 + tid] = z4;
        uint4 zb = {0u, 0u, 0u, 0u};
        if ((ln >> 4) == 0) zb.x = (unsigned)bfb(b2[ntb * 16 + (ln & 15)]);
        dst[512 + tid] = zb;
        uint4 zc = {0u, 0u, 0u, 0u};
        if ((ln >> 4) == 0) zc.x = (unsigned)bfb(cb1[ntb * 16 + (ln & 15)]);
        dst[1280 + tid] = zc;
        if (tid < 64) CW2S[tid] = cw2[tid];
    }

    // hoist W1 slices 0..3 into registers (loop-invariant; AGPR-parked, 64)
    bf16x8 w1f[4][4];
    #pragma unroll
    for (int s = 0; s < 4; ++s)
        #pragma unroll
        for (int nt = 0; nt < 4; ++nt)
            w1f[s][nt] = *(const bf16x8*)(w1b + ((s * 4 + nt) * 64 + lane) * 8);

    const float cb2s = cb2[0];

    // ones B-fragment: B[k=0][e]=1 for all e (bias K-slice driver)
    bf16x8 onef = {0, 0, 0, 0, 0, 0, 0, 0};
    if (quad == 0) onef[0] = (short)0x3F80;

    __syncthreads();   // WS/CW2S visible to all 4 waves

    // ---- pipeline prologue: records for tile 0 and 1, payload for tile 0 ----
    int bt  = blockIdx.x;
    int btn = bt + NB_EDGE;
    int2 rcv = *(const int2*)(rce + (size_t)((bt * 4 + w) * 16 + l15) * 24);
    int2 rcn = *(const int2*)(rce + (size_t)(((btn < NTILE ? btn : bt) * 4 + w) * 16 + l15) * 24);
    bf16x8 af0, af1, af2, af3;
    bf16x8 af4 = {0, 0, 0, 0, 0, 0, 0, 0};
    {
        const unsigned short* hr = hb + (size_t)rcv.x * HH + quad * 8;
        const unsigned short* hc = hb + (size_t)rcv.y * HH + quad * 8;
        af0 = *(const bf16x8*)(hr);
        af1 = *(const bf16x8*)(hr + 32);
        af2 = *(const bf16x8*)(hc);
        af3 = *(const bf16x8*)(hc + 32);
        if (quad == 0)
            af4 = ld_ef(rce + (size_t)((bt * 4 + w) * 16 + l15) * 24);
    }

    while (bt < NTILE) {
        // ---- consume: per-tile scalars (x4 read not prefetched; its latency
        // hides under G1's first 16 MFMAs since af4 only feeds the last slice)
        if (quad == 0) {
            RI[w][l15] = rcv.x;
        } else if (quad == 1) {
            const float4 xr = ((const float4*)x4)[rcv.x];
            const float4 xc = ((const float4*)x4)[rcv.y];
            const float rx = xr.x - xc.x;
            const float ry = xr.y - xc.y;
            const float rz = xr.z - xc.z;
            RV[w][l15][0] = rx; RV[w][l15][1] = ry; RV[w][l15][2] = rz;
            af4[0] = (short)bfb(rx * rx + ry * ry + rz * rz);
            af4[1] = (short)0x3F80;   // kp=137 constant-1 -> b1 bias row
        }

        // ---- GEMM1 swapped: lane holds H1[l15][nt*16+quad*4+rr] ----
        __builtin_amdgcn_s_setprio(1);
        #pragma unroll
        for (int nt = 0; nt < 4; ++nt) {
            f32x4 a = {0.f, 0.f, 0.f, 0.f};
            a = __builtin_amdgcn_mfma_f32_16x16x32_bf16(w1f[0][nt], af0, a, 0, 0, 0);
            a = __builtin_amdgcn_mfma_f32_16x16x32_bf16(w1f[1][nt], af1, a, 0, 0, 0);
            a = __builtin_amdgcn_mfma_f32_16x16x32_bf16(w1f[2][nt], af2, a, 0, 0, 0);
            a = __builtin_amdgcn_mfma_f32_16x16x32_bf16(w1f[3][nt], af3, a, 0, 0, 0);
            {
                bf16x8 b4 = *(const bf16x8*)&WS[12288 + (nt * 64 + lane) * 8];
                a = __builtin_amdgcn_mfma_f32_16x16x32_bf16(b4, af4, a, 0, 0, 0);
            }
            uint2 pkv;
            pkv.x = cvtpk(silu_f(a[0]), silu_f(a[1]));
            pkv.y = cvtpk(silu_f(a[2]), silu_f(a[3]));
            *(uint2*)&S[w][l15][nt * 16 + quad * 4] = pkv;   // row=e, cols n..n+3
        }
        __builtin_amdgcn_s_setprio(0);

        // ---- issue next tile's payload into the now-dead af regs ----
        {
            const int pn = ((btn < NTILE ? btn : bt) * 4 + w) * 16 + l15;
            const unsigned short* hr = hb + (size_t)rcn.x * HH + quad * 8;
            const unsigned short* hc = hb + (size_t)rcn.y * HH + quad * 8;
            af0 = *(const bf16x8*)(hr);
            af1 = *(const bf16x8*)(hr + 32);
            af2 = *(const bf16x8*)(hc);
            af3 = *(const bf16x8*)(hc + 32);
            if (quad == 0)
                af4 = ld_ef(rce + (size_t)pn * 24);
        }
        const int btn2 = btn + NB_EDGE;
        const int2 rcn2 = *(const int2*)(rce + (size_t)(((btn2 < NTILE ? btn2 : btn) * 4 + w) * 16 + l15) * 24);
        CFENCE();

        // ---- GEMM2 swapped: B-frags = H1[l15][s*32+quad*8..] from S ----
        bf16x8 h1f0 = *(const bf16x8*)&S[w][l15][quad * 8];
        bf16x8 h1f1 = *(const bf16x8*)&S[w][l15][32 + quad * 8];
        CFENCE();   // frags read (program-order) before msg overwrites
        __builtin_amdgcn_s_setprio(1);
        #pragma unroll
        for (int nt = 0; nt < 4; ++nt) {
            f32x4 m = {0.f, 0.f, 0.f, 0.f};
            {
                bf16x8 wf = *(const bf16x8*)&WS[((0 * 4 + nt) * 64 + lane) * 8];
                m = __builtin_amdgcn_mfma_f32_16x16x32_bf16(wf, h1f0, m, 0, 0, 0);
            }
            {
                bf16x8 wf = *(const bf16x8*)&WS[((1 * 4 + nt) * 64 + lane) * 8];
                m = __builtin_amdgcn_mfma_f32_16x16x32_bf16(wf, h1f1, m, 0, 0, 0);
            }
            {
                bf16x8 wb = *(const bf16x8*)&WS[4096 + (nt * 64 + lane) * 8];
                m = __builtin_amdgcn_mfma_f32_16x16x32_bf16(wb, onef, m, 0, 0, 0);
            }
            uint2 pkv;
            pkv.x = cvtpk(silu_f(m[0]), silu_f(m[1]));
            pkv.y = cvtpk(silu_f(m[2]), silu_f(m[3]));
            *(uint2*)&S[w][l15][nt * 16 + quad * 4] = pkv;   // msg[e][n]
        }
        __builtin_amdgcn_s_setprio(0);
        CFENCE();

        // ---- GEMM3 swapped: c1[l15][n]; lane-local dot with cw2 (LDS) ----
        bf16x8 mf0 = *(const bf16x8*)&S[w][l15][quad * 8];
        bf16x8 mf1 = *(const bf16x8*)&S[w][l15][32 + quad * 8];
        float pr = 0.f;
        __builtin_amdgcn_s_setprio(1);
        #pragma unroll
        for (int nt = 0; nt < 4; ++nt) {
            f32x4 q3 = {0.f, 0.f, 0.f, 0.f};
            {
                bf16x8 wf = *(const bf16x8*)&WS[6144 + ((0 * 4 + nt) * 64 + lane) * 8];
                q3 = __builtin_amdgcn_mfma_f32_16x16x32_bf16(wf, mf0, q3, 0, 0, 0);
            }
            {
                bf16x8 wf = *(const bf16x8*)&WS[6144 + ((1 * 4 + nt) * 64 + lane) * 8];
                q3 = __builtin_amdgcn_mfma_f32_16x16x32_bf16(wf, mf1, q3, 0, 0, 0);
            }
            {
                bf16x8 wb = *(const bf16x8*)&WS[10240 + (nt * 64 + lane) * 8];
                q3 = __builtin_amdgcn_mfma_f32_16x16x32_bf16(wb, onef, q3, 0, 0, 0);
            }
            const float4 cwv = *(const float4*)&CW2S[nt * 16 + quad * 4];
            pr += silu_f(q3[0]) * cwv.x;
            pr += silu_f(q3[1]) * cwv.y;
            pr += silu_f(q3[2]) * cwv.z;
            pr += silu_f(q3[3]) * cwv.w;
        }
        __builtin_amdgcn_s_setprio(0);
        pr += __shfl_xor(pr, 16, 64);    // reduce over the 4 quads of edge l15
        pr += __shfl_xor(pr, 32, 64);
        if (quad == 0) *(float*)&S[w][l15][64] = pr + cb2s;
        CFENCE();

        // ---- segmented flush: rows sorted by RI within the tile ----
        if (lane < 32) {   // msg -> tmsgb: lane owns cols {2l, 2l+1}, pk atomic
            unsigned both = *(const unsigned*)&S[w][0][2 * lane];
            float ax = b2f((unsigned short)(both & 0xffffu));
            float ay = b2f((unsigned short)(both >> 16));
            int cur_r = RI[w][0];
            #pragma unroll
            for (int g = 1; g < 16; ++g) {
                const int ri = RI[w][g];
                unsigned bv = *(const unsigned*)&S[w][g][2 * lane];
                const float vx = b2f((unsigned short)(bv & 0xffffu));
                const float vy = b2f((unsigned short)(bv >> 16));
                if (ri != cur_r) {
                    atomic_pk_bf16(&tmsgb[(size_t)cur_r * HH + 2 * lane], pk2(ax, ay));
                    ax = 0.f; ay = 0.f; cur_r = ri;
                }
                ax += vx; ay += vy;
            }
            atomic_pk_bf16(&tmsgb[(size_t)cur_r * HH + 2 * lane], pk2(ax, ay));
        } else if ((lane & 31) < 3) {   // f = rij*cm -> sum_f (fp32, tiny)
            const int sl = lane & 31;
            float acc = RV[w][0][sl] * (*(const float*)&S[w][0][64]);
            int cur_r = RI[w][0];
            #pragma unroll
            for (int g = 1; g < 16; ++g) {
                const int ri = RI[w][g];
                const float v = RV[w][g][sl] * (*(const float*)&S[w][g][64]);
                if (ri != cur_r) {
                    atomicAdd(&sum_f[3 * cur_r + sl], acc);
                    acc = 0.f; cur_r = ri;
                }
                acc += v;
            }
            atomicAdd(&sum_f[3 * cur_r + sl], acc);
        }
        CFENCE();   // flush reads ordered (program order) before next S writes

        // ---- rotate pipeline state ----
        bt = btn; btn = btn2; rcv = rcn; rcn = rcn2;
    }
}

// ---------------- MFMA node kernel: 16 nodes per wave ----------------
// Reads bf16 tmsgb directly. `last` guards dead cross-layer work:
//  layer 0 (!last): skip the f32 h store (layer 1 rewrites it); keep hb, x4,
//    and tmsgb/sum_f re-zeroing (layer 1 needs them).
//  layer 1 (last): write h + x only; skip hb, x4, and the re-zeroing
//    (setup re-zeroes on every launch, so iteration re-runs stay correct).
__global__ __launch_bounds__(256) void node_mfma_kernel(
    float* __restrict__ x, float* __restrict__ x4, float* __restrict__ h,
    unsigned short* __restrict__ hb,
    float* __restrict__ sum_f, const int* __restrict__ deg,
    unsigned short* __restrict__ tmsgb,
    const unsigned short* __restrict__ nw1b, const unsigned short* __restrict__ nw2b,
    const float* __restrict__ nb1, const float* __restrict__ nb2, int last)
{
    __shared__ __align__(16) unsigned short S[4][16][136];
    const int tid = threadIdx.x;
    const int w = tid >> 6, lane = tid & 63;
    const int l15 = lane & 15, quad = lane >> 4;
    const int le = lane >> 2, sub = lane & 3;
    const int t = blockIdx.x * 4 + w;
    if (t >= NN / 16) return;                      // 3125 waves exactly

    // gather (fully coalesced): [hb | tmsgb] -> S[16][128]; zero tmsgb after
    {
        unsigned short* Srow = &S[w][le][0];
        const int n = t * 16 + le;
        const unsigned short* hr = hb + (size_t)n * HH + sub * 16;
        *(uint4*)&Srow[sub * 16]     = *(const uint4*)(hr);
        *(uint4*)&Srow[sub * 16 + 8] = *(const uint4*)(hr + 8);
        unsigned short* tm = tmsgb + (size_t)n * HH + sub * 16;
        *(uint4*)&Srow[64 + sub * 16]     = *(const uint4*)(tm);
        *(uint4*)&Srow[64 + sub * 16 + 8] = *(const uint4*)(tm + 8);
        if (!last) {
            const uint4 z = {0u, 0u, 0u, 0u};
            *(uint4*)(tm)     = z;
            *(uint4*)(tm + 8) = z;
        }
    }
    // x update: one lane per node; zero sum_f after (unless last layer)
    if (lane < 16) {
        const int nn = t * 16 + lane;
        const float cn = fmaxf((float)deg[nn], 1.0f);
        const float rc = __builtin_amdgcn_rcpf(cn);
        #pragma unroll
        for (int d3 = 0; d3 < 3; ++d3) {
            float tf = sum_f[3 * nn + d3] * rc;
            tf = fminf(fmaxf(tf, -100.0f), 100.0f);
            x[3 * nn + d3] += tf;
            if (!last) {
                x4[4 * nn + d3] += tf;
                sum_f[3 * nn + d3] = 0.0f;
            }
        }
    }
    WFENCE();

    // GEMM1: [16x128] @ nW1[128x64] -> SiLU -> alias cols 0..63
    bf16x8 af[4];
    #pragma unroll
    for (int s = 0; s < 4; ++s)
        af[s] = *(const bf16x8*)&S[w][l15][s * 32 + quad * 8];
    WFENCE();
    float nb1v[4], nb2v[4];
    #pragma unroll
    for (int nt = 0; nt < 4; ++nt) {
        nb1v[nt] = nb1[nt * 16 + l15];
        nb2v[nt] = nb2[nt * 16 + l15];
    }
    #pragma unroll
    for (int nt = 0; nt < 4; ++nt) {
        f32x4 a = {0.f, 0.f, 0.f, 0.f};
        #pragma unroll
        for (int s = 0; s < 4; ++s) {
            bf16x8 bf = *(const bf16x8*)(nw1b + ((s * 4 + nt) * 64 + lane) * 8);
            a = __builtin_amdgcn_mfma_f32_16x16x32_bf16(af[s], bf, a, 0, 0, 0);
        }
        #pragma unroll
        for (int rr = 0; rr < 4; ++rr)
            S[w][quad * 4 + rr][nt * 16 + l15] = bfb(silu_f(a[rr] + nb1v[nt]));
    }
    WFENCE();

    // GEMM2: [16x64] @ nW2[64x64] -> h (no act)
    bf16x8 a2[2];
    #pragma unroll
    for (int s = 0; s < 2; ++s)
        a2[s] = *(const bf16x8*)&S[w][l15][s * 32 + quad * 8];
    #pragma unroll
    for (int nt = 0; nt < 4; ++nt) {
        f32x4 m = {0.f, 0.f, 0.f, 0.f};
        #pragma unroll
        for (int s = 0; s < 2; ++s) {
            bf16x8 bf = *(const bf16x8*)(nw2b + ((s * 4 + nt) * 64 + lane) * 8);
            m = __builtin_amdgcn_mfma_f32_16x16x32_bf16(a2[s], bf, m, 0, 0, 0);
        }
        #pragma unroll
        for (int rr = 0; rr < 4; ++rr) {
            const float v = m[rr] + nb2v[nt];
            const size_t nd = (size_t)(t * 16 + quad * 4 + rr) * HH + nt * 16 + l15;
            if (last) h[nd] = v;
            else      hb[nd] = bfb(v);
        }
    }
}

extern "C" void kernel_launch(void* const* d_in, const int* in_sizes, int n_in,
                              void* d_out, int out_size, void* d_ws, size_t ws_size,
                              hipStream_t stream) {
    const float* x_in  = (const float*)d_in[0];
    const float* h_in  = (const float*)d_in[1];
    const int*   row   = (const int*)d_in[2];
    const int*   col   = (const int*)d_in[3];
    const float* efea  = (const float*)d_in[4];
    const float* emb_W = (const float*)d_in[5];
    const float* emb_b = (const float*)d_in[6];
    const float* eW1   = (const float*)d_in[7];
    const float* eb1   = (const float*)d_in[8];
    const float* eW2   = (const float*)d_in[9];
    const float* eb2   = (const float*)d_in[10];
    const float* cW1   = (const float*)d_in[11];
    const float* cb1   = (const float*)d_in[12];
    const float* cW2   = (const float*)d_in[13];
    const float* cb2   = (const float*)d_in[14];
    const float* nW1   = (const float*)d_in[15];
    const float* nb1   = (const float*)d_in[16];
    const float* nW2   = (const float*)d_in[17];
    const float* nb2   = (const float*)d_in[18];

    float* out = (float*)d_out;
    float* xo = out;                 // N*3
    float* ho = out + NN * 3;        // N*64

    // workspace layout (8/16B-aligned segments)
    char* wsb = (char*)d_ws;
    float* sum_f = (float*)wsb;                                  //    600,000 B
    unsigned short* tmsgb = (unsigned short*)(wsb + 600000);     //  6,400,000 B
    char* rce   = wsb + 7000000;                                 // 19,200,000 B (24B recs)
    unsigned short* hb  = (unsigned short*)(wsb + 26200000);     //  6,400,000 B
    unsigned short* wsW = (unsigned short*)(wsb + 32600000);     //    122,880 B
    int* deg    = (int*)(wsb + 32722880);                        //    200,000 B
    int* gs     = (int*)(wsb + 32922880);                        //        800 B
    int* cur    = (int*)(wsb + 32923680);                        //    200,000 B
    float* x4   = (float*)(wsb + 33123680);                      //    800,000 B

    // zero deg+gs, then fused setup (hist + swizzle + embed + zero + x copies)
    hipMemsetAsync(deg, 0, 200800, stream);
    setup_kernel<<<11667, 256, 0, stream>>>(
        row, deg,
        eW1, eW2, cW1, nW1, nW2, wsW,
        h_in, emb_W, emb_b, hb,
        wsb, x_in, xo, x4);
    // fused decoupled-lookback scan + counting-sort fill
    scan_kernel<<<200, 256, 0, stream>>>(deg, gs, cur);
    fill_kernel<<<MM / 256, 256, 0, stream>>>(row, col, efea, cur, rce);

    for (int i = 0; i < 2; ++i) {
        const unsigned short* L = wsW + i * 30720;
        edge_mfma_kernel<<<NB_EDGE, 256, 0, stream>>>(
            x4, hb, rce,
            L, L + 10240, L + 14336,
            eb1 + i * 64, eb2 + i * 64, cb1 + i * 64, cW2 + i * 64, cb2 + i,
            sum_f, tmsgb);
        node_mfma_kernel<<<(NN / 16 + 3) / 4, 256, 0, stream>>>(
            xo, x4, ho, hb, sum_f, deg, tmsgb,
            L + 18432, L + 26624, nb1 + i * 64, nb2 + i * 64, i);
    }
}

// Round 14
// 376.799 us; speedup vs baseline: 1.0348x; 1.0289x over previous
//
#include <hip/hip_runtime.h>
#include <math.h>

#define NN 50000
#define MM 800000
#define HH 64
#define NB_EDGE 1024                // 4 blocks/CU exactly (39.4KB LDS x 4 = CU cap)
#define NTILE 12500                 // MM / 64 edges per block-tile

typedef short bf16x8 __attribute__((ext_vector_type(8)));
typedef float f32x4  __attribute__((ext_vector_type(4)));

// hard per-wave LDS drain (node kernel): lgkmcnt(0) + compiler barrier
#define WFENCE() asm volatile("s_waitcnt lgkmcnt(0)" ::: "memory")
// compiler-only barrier (edge kernel): pins code motion but lets the compiler
// emit minimal dependence-tracked lgkmcnt(N) waits (R12: -3us/dispatch).
#define CFENCE() asm volatile("" ::: "memory")

__device__ __forceinline__ float silu_f(float v) {
    return v * __builtin_amdgcn_rcpf(1.0f + __expf(-v));
}
// round-half-up fp32 -> bf16 bits (0.5 ulp max)
__device__ __forceinline__ unsigned short bfb(float a) {
    return (unsigned short)((__float_as_uint(a) + 0x8000u) >> 16);
}
// pack two f32 -> one u32 of 2 bf16 (low = lo, high = hi), single VALU op
__device__ __forceinline__ unsigned cvtpk(float lo, float hi) {
    unsigned r;
    asm("v_cvt_pk_bf16_f32 %0, %1, %2" : "=v"(r) : "v"(lo), "v"(hi));
    return r;
}
// pack two f32 -> bf16x2 via v_perm (low = a, high = b)
__device__ __forceinline__ unsigned pk2(float a, float b) {
    return __builtin_amdgcn_perm(__float_as_uint(b) + 0x8000u,
                                 __float_as_uint(a) + 0x8000u, 0x07060302u);
}
__device__ __forceinline__ float b2f(unsigned short s) {
    return __uint_as_float((unsigned)s << 16);
}
// packed bf16x2 atomic add
__device__ __forceinline__ void atomic_pk_bf16(unsigned short* addr, unsigned pk) {
    asm volatile("global_atomic_pk_add_bf16 %0, %1, off"
                 :: "v"((unsigned long long)(size_t)addr), "v"(pk) : "memory");
}
// load the 16B ef payload of a 24B edge record (8B-aligned) as a bf16x8
__device__ __forceinline__ bf16x8 ld_ef(const char* rp) {
    union { uint2 u[2]; bf16x8 v; } t;
    t.u[0] = *(const uint2*)(rp + 8);
    t.u[1] = *(const uint2*)(rp + 16);
    return t.v;
}

// ---------------- fused setup ----------------
// blocks [0,3125): deg histogram
// blocks [3125,3365): weight pre-swizzle (per layer 30720 shorts)
// blocks [3365,9615): embedding, 2 outputs/thread (hb only; f32 h is dead)
// blocks [9615,11324): zero sum_f+tmsgb (7,000,000 B)
// blocks [11324,11471): copy x_in -> xo (uint4)
// blocks [11471,11667): build padded x4 mirror
__global__ __launch_bounds__(256) void setup_kernel(
    const int* __restrict__ row, int* __restrict__ deg,
    const float* __restrict__ eW1, const float* __restrict__ eW2,
    const float* __restrict__ cW1, const float* __restrict__ nW1,
    const float* __restrict__ nW2, unsigned short* __restrict__ wsW,
    const float* __restrict__ h_in, const float* __restrict__ emb_W,
    const float* __restrict__ emb_b,
    unsigned short* __restrict__ hb,
    char* __restrict__ zbase, const float* __restrict__ x_in,
    float* __restrict__ xo, float* __restrict__ x4)
{
    const int b = blockIdx.x;
    if (b < 3125) {
        const int e = b * 256 + threadIdx.x;
        atomicAdd(&deg[row[e]], 1);
    } else if (b < 3365) {
        const int i = (b - 3125) * 256 + threadIdx.x;     // 0 .. 61439
        const int layer = i / 30720;
        const int rem = i - layer * 30720;
        float val;
        if (rem < 10240) {
            const int j = rem & 7, lane = (rem >> 3) & 63, nt = (rem >> 9) & 3, s = rem >> 11;
            const int kp = s * 32 + ((lane >> 4) << 3) + j;
            const int n  = nt * 16 + (lane & 15);
            if (kp > 136) val = 0.0f;
            else {
                const int k = (kp == 136) ? 0 : kp + 1;   // k'=136 is the r2 row
                val = eW1[layer * 137 * 64 + k * 64 + n];
            }
        } else if (rem < 14336) {
            const int r2 = rem - 10240;
            const int j = r2 & 7, lane = (r2 >> 3) & 63, nt = (r2 >> 9) & 3, s = r2 >> 11;
            val = eW2[layer * 4096 + (s * 32 + ((lane >> 4) << 3) + j) * 64 + nt * 16 + (lane & 15)];
        } else if (rem < 18432) {
            const int r3 = rem - 14336;
            const int j = r3 & 7, lane = (r3 >> 3) & 63, nt = (r3 >> 9) & 3, s = r3 >> 11;
            val = cW1[layer * 4096 + (s * 32 + ((lane >> 4) << 3) + j) * 64 + nt * 16 + (lane & 15)];
        } else if (rem < 26624) {
            const int r4 = rem - 18432;
            const int j = r4 & 7, lane = (r4 >> 3) & 63, nt = (r4 >> 9) & 3, s = r4 >> 11;
            const int kp = s * 32 + ((lane >> 4) << 3) + j;      // < 128
            val = nW1[layer * 8192 + kp * 64 + nt * 16 + (lane & 15)];
        } else {
            const int r5 = rem - 26624;
            const int j = r5 & 7, lane = (r5 >> 3) & 63, nt = (r5 >> 9) & 3, s = r5 >> 11;
            val = nW2[layer * 4096 + (s * 32 + ((lane >> 4) << 3) + j) * 64 + nt * 16 + (lane & 15)];
        }
        wsW[i] = bfb(val);
    } else if (b < 9615) {
        const int idx = (b - 3365) * 256 + threadIdx.x;   // over N*32
        const int n = idx >> 5, j2 = (idx & 31) * 2;
        float a0 = emb_b[j2], a1 = emb_b[j2 + 1];
        #pragma unroll
        for (int k = 0; k < 16; ++k) {
            const float hv = h_in[n * 16 + k];
            a0 += hv * emb_W[k * HH + j2];
            a1 += hv * emb_W[k * HH + j2 + 1];
        }
        *(unsigned*)&hb[n * HH + j2] = pk2(a0, a1);
    } else if (b < 11324) {
        const int t = (b - 9615) * 256 + threadIdx.x;
        if (t < 437500) {                                  // 7,000,000 / 16
            const uint4 z = {0u, 0u, 0u, 0u};
            *(uint4*)(zbase + (size_t)t * 16) = z;
        }
    } else if (b < 11471) {
        const int t = (b - 11324) * 256 + threadIdx.x;
        if (t < 37500)                                     // N*3 floats / 4
            ((uint4*)xo)[t] = ((const uint4*)x_in)[t];
    } else {
        const int n = (b - 11471) * 256 + threadIdx.x;
        if (n < NN) {
            float4 v;
            v.x = x_in[3 * n + 0];
            v.y = x_in[3 * n + 1];
            v.z = x_in[3 * n + 2];
            v.w = 0.0f;
            ((float4*)x4)[n] = v;
        }
    }
}

// fused scan (replaces scanA+scanB+scanC): 200 blocks, all co-resident.
// Each block scans its 250-node chunk, publishes its total to gs[b] (flag =
// sum+1, device-scope atomic), then spin-waits for all predecessors' totals
// (decoupled lookback; 200 blocks <= 256 CUs so all make progress), reduces
// them, and writes the exclusive global prefix into cur.
__global__ __launch_bounds__(256) void scan_kernel(const int* __restrict__ deg,
                                                   int* __restrict__ gs,
                                                   int* __restrict__ cur) {
    __shared__ int ps[256];
    __shared__ int red[4];
    const int t = threadIdx.x;
    const int b = blockIdx.x;
    const int base = b * 250;
    int v = (t < 250) ? deg[base + t] : 0;
    ps[t] = v;
    __syncthreads();
    for (int off = 1; off < 256; off <<= 1) {
        const int u = (t >= off) ? ps[t - off] : 0;
        __syncthreads();
        ps[t] += u;
        __syncthreads();
    }
    if (t == 255) atomicExch(&gs[b], ps[255] + 1);   // publish chunk total
    int pre = 0;
    if (t < b) {                                     // lookback on predecessors
        int u;
        do { u = atomicAdd(&gs[t], 0); } while (u == 0);
        pre = u - 1;
    }
    #pragma unroll
    for (int o = 1; o < 64; o <<= 1) pre += __shfl_xor(pre, o, 64);
    if ((t & 63) == 0) red[t >> 6] = pre;
    __syncthreads();
    if (t < 250) {
        const int boff = red[0] + red[1] + red[2] + red[3];
        cur[base + t] = boff + ps[t] - v;            // exclusive global prefix
    }
}

// one-pass counting-sort fill: ONE combined 24B record per edge
// [r:4 | c:4 | ef: 8 x bf16] written contiguously.
__global__ __launch_bounds__(256) void fill_kernel(
    const int* __restrict__ row, const int* __restrict__ col,
    const float* __restrict__ efea, int* __restrict__ cur,
    char* __restrict__ rce)
{
    const int e = blockIdx.x * 256 + threadIdx.x;
    const int r = row[e];
    const int pos = atomicAdd(&cur[r], 1);
    char* rp = rce + (size_t)pos * 24;
    int2 v; v.x = r; v.y = col[e];
    *(int2*)rp = v;
    const float4* ef = (const float4*)(efea + (size_t)e * 8);
    const float4 e0 = ef[0], e1 = ef[1];
    uint2 p0; p0.x = pk2(e0.x, e0.y); p0.y = pk2(e0.z, e0.w);
    uint2 p1; p1.x = pk2(e1.x, e1.y); p1.y = pk2(e1.z, e1.w);
    *(uint2*)(rp + 8)  = p0;
    *(uint2*)(rp + 16) = p1;
}

// ---------------- MFMA edge kernel: swapped operands + pipelined gather -----
// R13 structure: swapped MFMAs; biases folded via ones-fragment K-slices;
// gather pipelined one tile deep; setprio; CFENCE; grid 1024 = 4 blocks/CU;
// 24B combined edge records. R14: flush half-split -- the two exec-masked
// flush arms used to serialize (16-step msg chain THEN 16-step sum_f chain =
// 32 serial steps/tile). Now msg uses all 64 lanes over row-halves 0-7/8-15
// (8 steps; straddling segment -> two commuting atomics, ~1.5x atomic count,
// proven correct in R9) and sum_f uses 6 lanes over the same halves (8
// steps). Total serial depth 32 -> 16. Bank check: halves read rows g,g+8;
// +8 rows = 1152B == 0 mod 128 -> 2-way aliasing (free, m136).
__global__ __launch_bounds__(256, 4) void edge_mfma_kernel(
    const float* __restrict__ x4, const unsigned short* __restrict__ hb,
    const char* __restrict__ rce,
    const unsigned short* __restrict__ w1b, const unsigned short* __restrict__ w2b,
    const unsigned short* __restrict__ cw1b,
    const float* __restrict__ b1, const float* __restrict__ b2,
    const float* __restrict__ cb1, const float* __restrict__ cw2,
    const float* __restrict__ cb2,
    float* __restrict__ sum_f, unsigned short* __restrict__ tmsgb)
{
    __shared__ __align__(16) unsigned short S[4][16][72];  // [0,64)=H1/msg, [64,66)=cm f32
    __shared__ float RV[4][16][4];
    __shared__ int   RI[4][16];
    __shared__ __align__(16) unsigned short WS[14336];
    __shared__ __align__(16) float CW2S[64];
    // WS shorts: [0,4096)=w2 s0,s1   [4096,6144)=w2 bias slice
    //            [6144,10240)=cw1 s0,s1  [10240,12288)=cw1 bias slice
    //            [12288,14336)=w1 slice4 (kp137 patched with b1)

    const int tid = threadIdx.x;
    const int w = tid >> 6, lane = tid & 63;
    const int l15 = lane & 15, quad = lane >> 4;

    // stage weights + bias slices into LDS, block-shared
    {
        const uint4* s2 = (const uint4*)w2b;
        const uint4* s3 = (const uint4*)cw1b;
        const uint4* s4 = (const uint4*)w1b;   // slice4 = uint4 idx [1024,1280)
        uint4* dst = (uint4*)WS;
        dst[tid]        = s2[tid];
        dst[256 + tid]  = s2[256 + tid];
        dst[768 + tid]  = s3[tid];
        dst[1024 + tid] = s3[256 + tid];
        const int ln = tid & 63, ntb = tid >> 6;
        uint4 z4 = s4[1024 + tid];
        if ((ln >> 4) == 1)    // quad==1, j==1 slot = kp137 (high half of .x)
            z4.x = (z4.x & 0x0000FFFFu) | ((unsigned)bfb(b1[ntb * 16 + (ln & 15)]) << 16);
        dst[1536 + tid] = z4;
        uint4 zb = {0u, 0u, 0u, 0u};
        if ((ln >> 4) == 0) zb.x = (unsigned)bfb(b2[ntb * 16 + (ln & 15)]);
        dst[512 + tid] = zb;
        uint4 zc = {0u, 0u, 0u, 0u};
        if ((ln >> 4) == 0) zc.x = (unsigned)bfb(cb1[ntb * 16 + (ln & 15)]);
        dst[1280 + tid] = zc;
        if (tid < 64) CW2S[tid] = cw2[tid];
    }

    // hoist W1 slices 0..3 into registers (loop-invariant; AGPR-parked, 64)
    bf16x8 w1f[4][4];
    #pragma unroll
    for (int s = 0; s < 4; ++s)
        #pragma unroll
        for (int nt = 0; nt < 4; ++nt)
            w1f[s][nt] = *(const bf16x8*)(w1b + ((s * 4 + nt) * 64 + lane) * 8);

    const float cb2s = cb2[0];

    // ones B-fragment: B[k=0][e]=1 for all e (bias K-slice driver)
    bf16x8 onef = {0, 0, 0, 0, 0, 0, 0, 0};
    if (quad == 0) onef[0] = (short)0x3F80;

    __syncthreads();   // WS/CW2S visible to all 4 waves

    // ---- pipeline prologue: records for tile 0 and 1, payload for tile 0 ----
    int bt  = blockIdx.x;
    int btn = bt + NB_EDGE;
    int2 rcv = *(const int2*)(rce + (size_t)((bt * 4 + w) * 16 + l15) * 24);
    int2 rcn = *(const int2*)(rce + (size_t)(((btn < NTILE ? btn : bt) * 4 + w) * 16 + l15) * 24);
    bf16x8 af0, af1, af2, af3;
    bf16x8 af4 = {0, 0, 0, 0, 0, 0, 0, 0};
    {
        const unsigned short* hr = hb + (size_t)rcv.x * HH + quad * 8;
        const unsigned short* hc = hb + (size_t)rcv.y * HH + quad * 8;
        af0 = *(const bf16x8*)(hr);
        af1 = *(const bf16x8*)(hr + 32);
        af2 = *(const bf16x8*)(hc);
        af3 = *(const bf16x8*)(hc + 32);
        if (quad == 0)
            af4 = ld_ef(rce + (size_t)((bt * 4 + w) * 16 + l15) * 24);
    }

    while (bt < NTILE) {
        // ---- consume: per-tile scalars (x4 read not prefetched; its latency
        // hides under G1's first 16 MFMAs since af4 only feeds the last slice)
        if (quad == 0) {
            RI[w][l15] = rcv.x;
        } else if (quad == 1) {
            const float4 xr = ((const float4*)x4)[rcv.x];
            const float4 xc = ((const float4*)x4)[rcv.y];
            const float rx = xr.x - xc.x;
            const float ry = xr.y - xc.y;
            const float rz = xr.z - xc.z;
            RV[w][l15][0] = rx; RV[w][l15][1] = ry; RV[w][l15][2] = rz;
            af4[0] = (short)bfb(rx * rx + ry * ry + rz * rz);
            af4[1] = (short)0x3F80;   // kp=137 constant-1 -> b1 bias row
        }

        // ---- GEMM1 swapped: lane holds H1[l15][nt*16+quad*4+rr] ----
        __builtin_amdgcn_s_setprio(1);
        #pragma unroll
        for (int nt = 0; nt < 4; ++nt) {
            f32x4 a = {0.f, 0.f, 0.f, 0.f};
            a = __builtin_amdgcn_mfma_f32_16x16x32_bf16(w1f[0][nt], af0, a, 0, 0, 0);
            a = __builtin_amdgcn_mfma_f32_16x16x32_bf16(w1f[1][nt], af1, a, 0, 0, 0);
            a = __builtin_amdgcn_mfma_f32_16x16x32_bf16(w1f[2][nt], af2, a, 0, 0, 0);
            a = __builtin_amdgcn_mfma_f32_16x16x32_bf16(w1f[3][nt], af3, a, 0, 0, 0);
            {
                bf16x8 b4 = *(const bf16x8*)&WS[12288 + (nt * 64 + lane) * 8];
                a = __builtin_amdgcn_mfma_f32_16x16x32_bf16(b4, af4, a, 0, 0, 0);
            }
            uint2 pkv;
            pkv.x = cvtpk(silu_f(a[0]), silu_f(a[1]));
            pkv.y = cvtpk(silu_f(a[2]), silu_f(a[3]));
            *(uint2*)&S[w][l15][nt * 16 + quad * 4] = pkv;   // row=e, cols n..n+3
        }
        __builtin_amdgcn_s_setprio(0);

        // ---- issue next tile's payload into the now-dead af regs ----
        {
            const int pn = ((btn < NTILE ? btn : bt) * 4 + w) * 16 + l15;
            const unsigned short* hr = hb + (size_t)rcn.x * HH + quad * 8;
            const unsigned short* hc = hb + (size_t)rcn.y * HH + quad * 8;
            af0 = *(const bf16x8*)(hr);
            af1 = *(const bf16x8*)(hr + 32);
            af2 = *(const bf16x8*)(hc);
            af3 = *(const bf16x8*)(hc + 32);
            if (quad == 0)
                af4 = ld_ef(rce + (size_t)pn * 24);
        }
        const int btn2 = btn + NB_EDGE;
        const int2 rcn2 = *(const int2*)(rce + (size_t)(((btn2 < NTILE ? btn2 : btn) * 4 + w) * 16 + l15) * 24);
        CFENCE();

        // ---- GEMM2 swapped: B-frags = H1[l15][s*32+quad*8..] from S ----
        bf16x8 h1f0 = *(const bf16x8*)&S[w][l15][quad * 8];
        bf16x8 h1f1 = *(const bf16x8*)&S[w][l15][32 + quad * 8];
        CFENCE();   // frags read (program-order) before msg overwrites
        __builtin_amdgcn_s_setprio(1);
        #pragma unroll
        for (int nt = 0; nt < 4; ++nt) {
            f32x4 m = {0.f, 0.f, 0.f, 0.f};
            {
                bf16x8 wf = *(const bf16x8*)&WS[((0 * 4 + nt) * 64 + lane) * 8];
                m = __builtin_amdgcn_mfma_f32_16x16x32_bf16(wf, h1f0, m, 0, 0, 0);
            }
            {
                bf16x8 wf = *(const bf16x8*)&WS[((1 * 4 + nt) * 64 + lane) * 8];
                m = __builtin_amdgcn_mfma_f32_16x16x32_bf16(wf, h1f1, m, 0, 0, 0);
            }
            {
                bf16x8 wb = *(const bf16x8*)&WS[4096 + (nt * 64 + lane) * 8];
                m = __builtin_amdgcn_mfma_f32_16x16x32_bf16(wb, onef, m, 0, 0, 0);
            }
            uint2 pkv;
            pkv.x = cvtpk(silu_f(m[0]), silu_f(m[1]));
            pkv.y = cvtpk(silu_f(m[2]), silu_f(m[3]));
            *(uint2*)&S[w][l15][nt * 16 + quad * 4] = pkv;   // msg[e][n]
        }
        __builtin_amdgcn_s_setprio(0);
        CFENCE();

        // ---- GEMM3 swapped: c1[l15][n]; lane-local dot with cw2 (LDS) ----
        bf16x8 mf0 = *(const bf16x8*)&S[w][l15][quad * 8];
        bf16x8 mf1 = *(const bf16x8*)&S[w][l15][32 + quad * 8];
        float pr = 0.f;
        __builtin_amdgcn_s_setprio(1);
        #pragma unroll
        for (int nt = 0; nt < 4; ++nt) {
            f32x4 q3 = {0.f, 0.f, 0.f, 0.f};
            {
                bf16x8 wf = *(const bf16x8*)&WS[6144 + ((0 * 4 + nt) * 64 + lane) * 8];
                q3 = __builtin_amdgcn_mfma_f32_16x16x32_bf16(wf, mf0, q3, 0, 0, 0);
            }
            {
                bf16x8 wf = *(const bf16x8*)&WS[6144 + ((1 * 4 + nt) * 64 + lane) * 8];
                q3 = __builtin_amdgcn_mfma_f32_16x16x32_bf16(wf, mf1, q3, 0, 0, 0);
            }
            {
                bf16x8 wb = *(const bf16x8*)&WS[10240 + (nt * 64 + lane) * 8];
                q3 = __builtin_amdgcn_mfma_f32_16x16x32_bf16(wb, onef, q3, 0, 0, 0);
            }
            const float4 cwv = *(const float4*)&CW2S[nt * 16 + quad * 4];
            pr += silu_f(q3[0]) * cwv.x;
            pr += silu_f(q3[1]) * cwv.y;
            pr += silu_f(q3[2]) * cwv.z;
            pr += silu_f(q3[3]) * cwv.w;
        }
        __builtin_amdgcn_s_setprio(0);
        pr += __shfl_xor(pr, 16, 64);    // reduce over the 4 quads of edge l15
        pr += __shfl_xor(pr, 32, 64);
        if (quad == 0) *(float*)&S[w][l15][64] = pr + cb2s;
        CFENCE();

        // ---- flush, half-split: msg on all 64 lanes (rows 0-7 / 8-15),
        // then sum_f on 6 lanes. Serial depth 16 (was 32 with the two
        // exec-masked 16-step arms serializing). Straddling segments emit
        // one extra commuting atomic per half boundary.
        {
            const int half = lane >> 5;          // 0: rows 0-7, 1: rows 8-15
            const int colp = lane & 31;          // column pair {2c, 2c+1}
            const int rb = half * 8;
            unsigned both = *(const unsigned*)&S[w][rb][2 * colp];
            float ax = b2f((unsigned short)(both & 0xffffu));
            float ay = b2f((unsigned short)(both >> 16));
            int cur_r = RI[w][rb];
            #pragma unroll
            for (int g = 1; g < 8; ++g) {
                const int ri = RI[w][rb + g];
                unsigned bv = *(const unsigned*)&S[w][rb + g][2 * colp];
                const float vx = b2f((unsigned short)(bv & 0xffffu));
                const float vy = b2f((unsigned short)(bv >> 16));
                if (ri != cur_r) {
                    atomic_pk_bf16(&tmsgb[(size_t)cur_r * HH + 2 * colp], pk2(ax, ay));
                    ax = 0.f; ay = 0.f; cur_r = ri;
                }
                ax += vx; ay += vy;
            }
            atomic_pk_bf16(&tmsgb[(size_t)cur_r * HH + 2 * colp], pk2(ax, ay));
        }
        if (lane < 6) {     // sum_f: (half, dim) per lane, 8-step segments
            const int half = (lane >= 3) ? 1 : 0;
            const int sl = lane - half * 3;
            const int rb = half * 8;
            float acc = RV[w][rb][sl] * (*(const float*)&S[w][rb][64]);
            int cur_r = RI[w][rb];
            #pragma unroll
            for (int g = 1; g < 8; ++g) {
                const int ri = RI[w][rb + g];
                const float v = RV[w][rb + g][sl] * (*(const float*)&S[w][rb + g][64]);
                if (ri != cur_r) {
                    atomicAdd(&sum_f[3 * cur_r + sl], acc);
                    acc = 0.f; cur_r = ri;
                }
                acc += v;
            }
            atomicAdd(&sum_f[3 * cur_r + sl], acc);
        }
        CFENCE();   // flush reads ordered (program order) before next S writes

        // ---- rotate pipeline state ----
        bt = btn; btn = btn2; rcv = rcn; rcn = rcn2;
    }
}

// ---------------- MFMA node kernel: 16 nodes per wave ----------------
// Reads bf16 tmsgb directly. `last` guards dead cross-layer work:
//  layer 0 (!last): skip the f32 h store (layer 1 rewrites it); keep hb, x4,
//    and tmsgb/sum_f re-zeroing (layer 1 needs them).
//  layer 1 (last): write h + x only; skip hb, x4, and the re-zeroing
//    (setup re-zeroes on every launch, so iteration re-runs stay correct).
__global__ __launch_bounds__(256) void node_mfma_kernel(
    float* __restrict__ x, float* __restrict__ x4, float* __restrict__ h,
    unsigned short* __restrict__ hb,
    float* __restrict__ sum_f, const int* __restrict__ deg,
    unsigned short* __restrict__ tmsgb,
    const unsigned short* __restrict__ nw1b, const unsigned short* __restrict__ nw2b,
    const float* __restrict__ nb1, const float* __restrict__ nb2, int last)
{
    __shared__ __align__(16) unsigned short S[4][16][136];
    const int tid = threadIdx.x;
    const int w = tid >> 6, lane = tid & 63;
    const int l15 = lane & 15, quad = lane >> 4;
    const int le = lane >> 2, sub = lane & 3;
    const int t = blockIdx.x * 4 + w;
    if (t >= NN / 16) return;                      // 3125 waves exactly

    // gather (fully coalesced): [hb | tmsgb] -> S[16][128]; zero tmsgb after
    {
        unsigned short* Srow = &S[w][le][0];
        const int n = t * 16 + le;
        const unsigned short* hr = hb + (size_t)n * HH + sub * 16;
        *(uint4*)&Srow[sub * 16]     = *(const uint4*)(hr);
        *(uint4*)&Srow[sub * 16 + 8] = *(const uint4*)(hr + 8);
        unsigned short* tm = tmsgb + (size_t)n * HH + sub * 16;
        *(uint4*)&Srow[64 + sub * 16]     = *(const uint4*)(tm);
        *(uint4*)&Srow[64 + sub * 16 + 8] = *(const uint4*)(tm + 8);
        if (!last) {
            const uint4 z = {0u, 0u, 0u, 0u};
            *(uint4*)(tm)     = z;
            *(uint4*)(tm + 8) = z;
        }
    }
    // x update: one lane per node; zero sum_f after (unless last layer)
    if (lane < 16) {
        const int nn = t * 16 + lane;
        const float cn = fmaxf((float)deg[nn], 1.0f);
        const float rc = __builtin_amdgcn_rcpf(cn);
        #pragma unroll
        for (int d3 = 0; d3 < 3; ++d3) {
            float tf = sum_f[3 * nn + d3] * rc;
            tf = fminf(fmaxf(tf, -100.0f), 100.0f);
            x[3 * nn + d3] += tf;
            if (!last) {
                x4[4 * nn + d3] += tf;
                sum_f[3 * nn + d3] = 0.0f;
            }
        }
    }
    WFENCE();

    // GEMM1: [16x128] @ nW1[128x64] -> SiLU -> alias cols 0..63
    bf16x8 af[4];
    #pragma unroll
    for (int s = 0; s < 4; ++s)
        af[s] = *(const bf16x8*)&S[w][l15][s * 32 + quad * 8];
    WFENCE();
    float nb1v[4], nb2v[4];
    #pragma unroll
    for (int nt = 0; nt < 4; ++nt) {
        nb1v[nt] = nb1[nt * 16 + l15];
        nb2v[nt] = nb2[nt * 16 + l15];
    }
    #pragma unroll
    for (int nt = 0; nt < 4; ++nt) {
        f32x4 a = {0.f, 0.f, 0.f, 0.f};
        #pragma unroll
        for (int s = 0; s < 4; ++s) {
            bf16x8 bf = *(const bf16x8*)(nw1b + ((s * 4 + nt) * 64 + lane) * 8);
            a = __builtin_amdgcn_mfma_f32_16x16x32_bf16(af[s], bf, a, 0, 0, 0);
        }
        #pragma unroll
        for (int rr = 0; rr < 4; ++rr)
            S[w][quad * 4 + rr][nt * 16 + l15] = bfb(silu_f(a[rr] + nb1v[nt]));
    }
    WFENCE();

    // GEMM2: [16x64] @ nW2[64x64] -> h (no act)
    bf16x8 a2[2];
    #pragma unroll
    for (int s = 0; s < 2; ++s)
        a2[s] = *(const bf16x8*)&S[w][l15][s * 32 + quad * 8];
    #pragma unroll
    for (int nt = 0; nt < 4; ++nt) {
        f32x4 m = {0.f, 0.f, 0.f, 0.f};
        #pragma unroll
        for (int s = 0; s < 2; ++s) {
            bf16x8 bf = *(const bf16x8*)(nw2b + ((s * 4 + nt) * 64 + lane) * 8);
            m = __builtin_amdgcn_mfma_f32_16x16x32_bf16(a2[s], bf, m, 0, 0, 0);
        }
        #pragma unroll
        for (int rr = 0; rr < 4; ++rr) {
            const float v = m[rr] + nb2v[nt];
            const size_t nd = (size_t)(t * 16 + quad * 4 + rr) * HH + nt * 16 + l15;
            if (last) h[nd] = v;
            else      hb[nd] = bfb(v);
        }
    }
}

extern "C" void kernel_launch(void* const* d_in, const int* in_sizes, int n_in,
                              void* d_out, int out_size, void* d_ws, size_t ws_size,
                              hipStream_t stream) {
    const float* x_in  = (const float*)d_in[0];
    const float* h_in  = (const float*)d_in[1];
    const int*   row   = (const int*)d_in[2];
    const int*   col   = (const int*)d_in[3];
    const float* efea  = (const float*)d_in[4];
    const float* emb_W = (const float*)d_in[5];
    const float* emb_b = (const float*)d_in[6];
    const float* eW1   = (const float*)d_in[7];
    const float* eb1   = (const float*)d_in[8];
    const float* eW2   = (const float*)d_in[9];
    const float* eb2   = (const float*)d_in[10];
    const float* cW1   = (const float*)d_in[11];
    const float* cb1   = (const float*)d_in[12];
    const float* cW2   = (const float*)d_in[13];
    const float* cb2   = (const float*)d_in[14];
    const float* nW1   = (const float*)d_in[15];
    const float* nb1   = (const float*)d_in[16];
    const float* nW2   = (const float*)d_in[17];
    const float* nb2   = (const float*)d_in[18];

    float* out = (float*)d_out;
    float* xo = out;                 // N*3
    float* ho = out + NN * 3;        // N*64

    // workspace layout (8/16B-aligned segments)
    char* wsb = (char*)d_ws;
    float* sum_f = (float*)wsb;                                  //    600,000 B
    unsigned short* tmsgb = (unsigned short*)(wsb + 600000);     //  6,400,000 B
    char* rce   = wsb + 7000000;                                 // 19,200,000 B (24B recs)
    unsigned short* hb  = (unsigned short*)(wsb + 26200000);     //  6,400,000 B
    unsigned short* wsW = (unsigned short*)(wsb + 32600000);     //    122,880 B
    int* deg    = (int*)(wsb + 32722880);                        //    200,000 B
    int* gs     = (int*)(wsb + 32922880);                        //        800 B
    int* cur    = (int*)(wsb + 32923680);                        //    200,000 B
    float* x4   = (float*)(wsb + 33123680);                      //    800,000 B

    // zero deg+gs, then fused setup (hist + swizzle + embed + zero + x copies)
    hipMemsetAsync(deg, 0, 200800, stream);
    setup_kernel<<<11667, 256, 0, stream>>>(
        row, deg,
        eW1, eW2, cW1, nW1, nW2, wsW,
        h_in, emb_W, emb_b, hb,
        wsb, x_in, xo, x4);
    // fused decoupled-lookback scan + counting-sort fill
    scan_kernel<<<200, 256, 0, stream>>>(deg, gs, cur);
    fill_kernel<<<MM / 256, 256, 0, stream>>>(row, col, efea, cur, rce);

    for (int i = 0; i < 2; ++i) {
        const unsigned short* L = wsW + i * 30720;
        edge_mfma_kernel<<<NB_EDGE, 256, 0, stream>>>(
            x4, hb, rce,
            L, L + 10240, L + 14336,
            eb1 + i * 64, eb2 + i * 64, cb1 + i * 64, cW2 + i * 64, cb2 + i,
            sum_f, tmsgb);
        node_mfma_kernel<<<(NN / 16 + 3) / 4, 256, 0, stream>>>(
            xo, x4, ho, hb, sum_f, deg, tmsgb,
            L + 18432, L + 26624, nb1 + i * 64, nb2 + i * 64, i);
    }
}